// Round 8
// baseline (243.532 us; speedup 1.0000x reference)
//
#include <hip/hip_runtime.h>

// Causal self-attention, B=2 T=4096 C=768 H=12 D=64, bf16 MFMA pipeline:
//   cast x -> bf16; transpose W_attn/W_proj -> [N,K] bf16
//   GEMM (BK=64, XOR-swizzled global_load_lds staging, 32 MFMA per barrier-pair)
//   GEMM1 -> Q[b,h,t,d], K[b,h,t,d] (pre-scaled log2e/8), V^T[b,h,d,t]; LDS-transposed epilogue
//   attention: no online max; causal pairing (block p: q-tiles {p,63-p}); V-frags read
//     once per tile (shared across halves); row-sum l via ones-MFMA (no VALU adds/shuffles)
//   GEMM2 -> out fp32

#define TSEQ   4096
#define NHEAD  12
#define CDIM   768
#define C3     2304
#define BT_TOT 8192   // B*T

#define PSTR   72     // P-tile LDS row stride in shorts (64 keys + 8 pad; multiple of 8 for b128)

typedef __bf16 bf16x8 __attribute__((ext_vector_type(8)));
typedef __bf16 bf16x2 __attribute__((ext_vector_type(2)));
typedef float  f32x4  __attribute__((ext_vector_type(4)));

__device__ __forceinline__ unsigned short f2bf(float f) {
  unsigned int u = __builtin_bit_cast(unsigned int, f);
  u += 0x7FFFu + ((u >> 16) & 1u);            // round-to-nearest-even
  return (unsigned short)(u >> 16);
}

// native gfx950 f32->bf16 (v_cvt_pk_bf16_f32) — 1 instr per pair
__device__ __forceinline__ unsigned int pack2bf(float a, float b) {
  bf16x2 v = {(__bf16)a, (__bf16)b};
  return __builtin_bit_cast(unsigned int, v);
}

__device__ __forceinline__ f32x4 mfma16(bf16x8 a, bf16x8 b, f32x4 c) {
  return __builtin_amdgcn_mfma_f32_16x16x32_bf16(a, b, c, 0, 0, 0);
}

typedef const __attribute__((address_space(1))) void* gas_ptr;
typedef __attribute__((address_space(3))) void* las_ptr;

// lgkmcnt(0) ONLY — vmcnt/expcnt untouched so outstanding global/staging loads
// are NOT drained (inline asm with "memory" clobber would force vmcnt(0) — m131/m135).
#define LGKM_WAIT() __builtin_amdgcn_s_waitcnt(0xC07F)

// ---------------- prologue casts ----------------

__global__ __launch_bounds__(256) void cast_f32_bf16(const float* __restrict__ x,
                                                     unsigned short* __restrict__ o, int n) {
  int i = (blockIdx.x * 256 + threadIdx.x) * 4;
  if (i < n) {
    float4 v = *(const float4*)(x + i);
    ushort4 u;
    u.x = f2bf(v.x); u.y = f2bf(v.y); u.z = f2bf(v.z); u.w = f2bf(v.w);
    *(ushort4*)(o + i) = u;
  }
}

// dst[n][k] = bf16(src[k][n]);  K,N multiples of 32
__global__ __launch_bounds__(256) void transpose_cast(const float* __restrict__ src,
                                                      unsigned short* __restrict__ dst,
                                                      int K, int N) {
  __shared__ float tile[32][33];
  int n0 = blockIdx.x * 32, k0 = blockIdx.y * 32;
  int tx = threadIdx.x, ty = threadIdx.y;  // 32 x 8
#pragma unroll
  for (int i = 0; i < 4; ++i)
    tile[ty + i * 8][tx] = src[(size_t)(k0 + ty + i * 8) * N + n0 + tx];
  __syncthreads();
#pragma unroll
  for (int i = 0; i < 4; ++i)
    dst[(size_t)(n0 + ty + i * 8) * K + k0 + tx] = f2bf(tile[tx][ty + i * 8]);
}

// ------------- GEMM core (C = A[M,K] * BT[N,K]^T), 128x128 tile, BK=64, swizzled -------------
// LDS tiles 128 rows x 64 shorts (128B rows). 16B chunk at slot s of row r holds global
// chunk s ^ (r&7) (swizzle folded into the per-lane GLOBAL address at staging time), so
// frag ds_read_b128 at slot (kk*4+quad)^(l16&7) spreads 16 lanes over 32 banks (2-way, free).

__device__ __forceinline__ void gemm_bt_mainloop64(const unsigned short* __restrict__ A,
                                                   const unsigned short* __restrict__ BTm,
                                                   int K, int m0, int n0,
                                                   unsigned short* lds, f32x4 acc[4][4]) {
  const int tid = threadIdx.x;
  const int wave = tid >> 6, lane = tid & 63;
  const int quad = lane >> 4, l16 = lane & 15;
  const int wm = (wave >> 1) * 64, wn = (wave & 1) * 64;
  const int srow = lane >> 3;                     // 0..7
  const int scol = ((lane & 7) ^ srow) * 8;       // swizzled source chunk (shorts)

  for (int k0 = 0; k0 < K; k0 += 64) {
    __syncthreads();  // prior iter's ds_reads done before restaging
#pragma unroll
    for (int c = 0; c < 4; ++c) {
      const int grow = c * 32 + wave * 8 + srow;
      __builtin_amdgcn_global_load_lds((gas_ptr)(A + (size_t)(m0 + grow) * K + k0 + scol),
                                       (las_ptr)(lds + c * 2048 + wave * 512), 16, 0, 0);
      __builtin_amdgcn_global_load_lds((gas_ptr)(BTm + (size_t)(n0 + grow) * K + k0 + scol),
                                       (las_ptr)(lds + 8192 + c * 2048 + wave * 512), 16, 0, 0);
    }
    __syncthreads();  // staging visible

#pragma unroll
    for (int kk = 0; kk < 2; ++kk) {
      const int chunk = ((kk * 4 + quad) ^ (l16 & 7)) * 8;
      bf16x8 af[4], bfr[4];
#pragma unroll
      for (int i = 0; i < 4; ++i) {
        af[i]  = *(const bf16x8*)(lds + (wm + i * 16 + l16) * 64 + chunk);
        bfr[i] = *(const bf16x8*)(lds + 8192 + (wn + i * 16 + l16) * 64 + chunk);
      }
#pragma unroll
      for (int i = 0; i < 4; ++i)
#pragma unroll
        for (int j = 0; j < 4; ++j)
          acc[i][j] = mfma16(af[i], bfr[j], acc[i][j]);
    }
  }
}

// GEMM1: qkv = x@W_attn + b_attn -> Q/K (b,h,t,d) and V^T (b,h,d,t), bf16.
// K pre-scaled by log2e/8. Epilogue: tile -> LDS (transposed for V), then coalesced 16B stores.
__global__ __launch_bounds__(256) void gemm_qkv_kernel(
    const unsigned short* __restrict__ A, const unsigned short* __restrict__ BTm,
    const float* __restrict__ bias,
    unsigned short* __restrict__ qbuf, unsigned short* __restrict__ kbuf,
    unsigned short* __restrict__ vtbuf) {
  __shared__ __align__(16) unsigned short lds[128 * 136];  // mainloop uses first 16384
  f32x4 zero = {0.f, 0.f, 0.f, 0.f};
  f32x4 acc[4][4];
#pragma unroll
  for (int i = 0; i < 4; ++i)
#pragma unroll
    for (int j = 0; j < 4; ++j) acc[i][j] = zero;

  const int m0 = blockIdx.y * 128, n0 = blockIdx.x * 128;
  gemm_bt_mainloop64(A, BTm, CDIM, m0, n0, lds, acc);

  const int tid = threadIdx.x;
  const int wave = tid >> 6, lane = tid & 63;
  const int quad = lane >> 4, l16 = lane & 15;
  const int wm = (wave >> 1) * 64, wn = (wave & 1) * 64;
  const float KSCALE = 0.125f * 1.44269504088896340736f;  // 1/sqrt(64) * log2(e)

  const int seg = n0 / CDIM;   // 0=Q 1=K 2=V — uniform per block (128 | 768)
  const float mult = (seg == 1) ? KSCALE : 1.0f;

  __syncthreads();  // mainloop LDS reads done before epilogue reuse
#pragma unroll
  for (int j = 0; j < 4; ++j) {
    const int nl = wn + j * 16 + l16;
    const float bv = bias[n0 + nl];
#pragma unroll
    for (int i = 0; i < 4; ++i) {
#pragma unroll
      for (int r = 0; r < 4; ++r) {
        const int ml = wm + i * 16 + quad * 4 + r;
        unsigned short val = f2bf((acc[i][j][r] + bv) * mult);
        if (seg < 2) lds[ml * 136 + nl] = val;   // [t][n] for Q/K
        else         lds[nl * 136 + ml] = val;   // [n][t] for V^T
      }
    }
  }
  __syncthreads();

  const int row = tid >> 1, half = tid & 1;
  const unsigned short* src = lds + row * 136 + half * 64;
  unsigned short* dst;
  if (seg < 2) {
    const int m = m0 + row, b = m >> 12, t = m & (TSEQ - 1);
    const int nn = (n0 - seg * CDIM) + half * 64;   // multiple of 64
    const int h = nn >> 6;
    unsigned short* base = (seg == 0) ? qbuf : kbuf;
    dst = base + ((size_t)(b * NHEAD + h) * TSEQ + t) * 64;
  } else {
    const int nn = (n0 - 2 * CDIM) + row;
    const int h = nn >> 6, d = nn & 63;
    const int b = m0 >> 12, t0 = (m0 & (TSEQ - 1)) + half * 64;
    dst = vtbuf + ((size_t)(b * NHEAD + h) * 64 + d) * TSEQ + t0;
  }
#pragma unroll
  for (int k = 0; k < 8; ++k)
    *(uint4*)(dst + k * 8) = *(const uint4*)(src + k * 8);
}

// GEMM2: out = y@W_proj + b_proj (fp32 out)
__global__ __launch_bounds__(256) void gemm_out_kernel(
    const unsigned short* __restrict__ A, const unsigned short* __restrict__ BTm,
    const float* __restrict__ bias, float* __restrict__ out) {
  __shared__ __align__(16) unsigned short lds[16384];
  f32x4 zero = {0.f, 0.f, 0.f, 0.f};
  f32x4 acc[4][4];
#pragma unroll
  for (int i = 0; i < 4; ++i)
#pragma unroll
    for (int j = 0; j < 4; ++j) acc[i][j] = zero;

  const int m0 = blockIdx.y * 128, n0 = blockIdx.x * 128;
  gemm_bt_mainloop64(A, BTm, CDIM, m0, n0, lds, acc);

  const int tid = threadIdx.x;
  const int wave = tid >> 6, lane = tid & 63;
  const int quad = lane >> 4, l16 = lane & 15;
  const int wm = (wave >> 1) * 64, wn = (wave & 1) * 64;

#pragma unroll
  for (int j = 0; j < 4; ++j) {
    int n = n0 + wn + j * 16 + l16;
    float bv = bias[n];
#pragma unroll
    for (int i = 0; i < 4; ++i) {
#pragma unroll
      for (int r = 0; r < 4; ++r) {
        int m = m0 + wm + i * 16 + quad * 4 + r;
        out[(size_t)m * CDIM + n] = acc[i][j][r] + bv;
      }
    }
  }
}

// ---------------- attention ----------------
// S^T orientation: A=K (m=key), B=Q (n=q). C layout: col(l16)=q, row(quad*4+r)=key.
// Causal pairing: block p serves q-tile p (half A) and q-tile 63-p (half B) off one
// shared staged key stream. V-frags read ONCE per tile (shared by both halves).
// Row-sum l accumulated by MFMA against a ones fragment (C-layout rows align with o).

__device__ __forceinline__ void stage_kv4(const unsigned short* __restrict__ Kp,
                                          const unsigned short* __restrict__ Vp,
                                          int j0, unsigned short* kb, unsigned short* vb,
                                          int tid, int wave) {
  const int row = tid >> 3;                              // 0..31
  const int col = ((tid & 7) ^ (row & 7)) * 8;           // swizzle: (row+32)&7 == row&7
  __builtin_amdgcn_global_load_lds((gas_ptr)(Kp + (size_t)(j0 + row) * 64 + col),
                                   (las_ptr)(kb + wave * 512), 16, 0, 0);
  __builtin_amdgcn_global_load_lds((gas_ptr)(Kp + (size_t)(j0 + 32 + row) * 64 + col),
                                   (las_ptr)(kb + 2048 + wave * 512), 16, 0, 0);
  __builtin_amdgcn_global_load_lds((gas_ptr)(Vp + (size_t)row * TSEQ + j0 + col),
                                   (las_ptr)(vb + wave * 512), 16, 0, 0);
  __builtin_amdgcn_global_load_lds((gas_ptr)(Vp + (size_t)(row + 32) * TSEQ + j0 + col),
                                   (las_ptr)(vb + 2048 + wave * 512), 16, 0, 0);
}

__device__ __forceinline__ void qk_score(const bf16x8 kf[8], const bf16x8 qf[2], f32x4 s[4]) {
  f32x4 zero = {0.f, 0.f, 0.f, 0.f};
#pragma unroll
  for (int i = 0; i < 4; ++i)
    s[i] = mfma16(kf[2 * i + 1], qf[1], mfma16(kf[2 * i], qf[0], zero));
}

template <bool MASKED>
__device__ __forceinline__ void exp_write(const f32x4 s[4], unsigned short* __restrict__ prow,
                                          int j0, int q0, int l16, int quad) {
#pragma unroll
  for (int i = 0; i < 4; ++i) {
    float p[4];
#pragma unroll
    for (int r = 0; r < 4; ++r) {
      p[r] = __builtin_amdgcn_exp2f(s[i][r]);
      if (MASKED) {
        if (j0 + i * 16 + quad * 4 + r > q0 + l16) p[r] = 0.f;
      }
    }
    uint2 w;
    w.x = pack2bf(p[0], p[1]);
    w.y = pack2bf(p[2], p[3]);
    *(uint2*)(prow + l16 * PSTR + i * 16 + quad * 4) = w;   // ds_write_b64
  }
}

__global__ __launch_bounds__(256, 3) void attn_kernel(const unsigned short* __restrict__ qbuf,
                                                      const unsigned short* __restrict__ kbuf,
                                                      const unsigned short* __restrict__ vtbuf,
                                                      unsigned short* __restrict__ y) {
  __shared__ __align__(16) unsigned short k_lds[2][64 * 64];      // 2 x 8KB
  __shared__ __align__(16) unsigned short v_lds[2][64 * 64];      // 2 x 8KB
  __shared__ __align__(16) unsigned short p_lds[4][2][16 * PSTR]; // 18KB

  const int tid = threadIdx.x;
  const int wave = tid >> 6, lane = tid & 63;
  const int quad = lane >> 4, l16 = lane & 15;

  const int bh = blockIdx.x % 24;
  const int p = blockIdx.x / 24;            // 0..31; p=0 (most staging) dispatches first
  const int qA0 = p * 64 + wave * 16;       // short half: tiles 0..p
  const int qB0 = (63 - p) * 64 + wave * 16;// long half:  tiles 0..63-p

  const unsigned short* Qp = qbuf + (size_t)bh * TSEQ * 64;
  const unsigned short* Kp = kbuf + (size_t)bh * TSEQ * 64;
  const unsigned short* Vp = vtbuf + (size_t)bh * 64 * TSEQ;
  unsigned short* prowA = &p_lds[wave][0][0];
  unsigned short* prowB = &p_lds[wave][1][0];

  bf16x8 qfA[2], qfB[2];
  qfA[0] = *(const bf16x8*)(Qp + (size_t)(qA0 + l16) * 64 + quad * 8);
  qfA[1] = *(const bf16x8*)(Qp + (size_t)(qA0 + l16) * 64 + 32 + quad * 8);
  qfB[0] = *(const bf16x8*)(Qp + (size_t)(qB0 + l16) * 64 + quad * 8);
  qfB[1] = *(const bf16x8*)(Qp + (size_t)(qB0 + l16) * 64 + 32 + quad * 8);

  const bf16x8 ones = {(__bf16)1.f, (__bf16)1.f, (__bf16)1.f, (__bf16)1.f,
                       (__bf16)1.f, (__bf16)1.f, (__bf16)1.f, (__bf16)1.f};

  f32x4 zero = {0.f, 0.f, 0.f, 0.f};
  f32x4 oA[4], oB[4], lA = zero, lB = zero;
#pragma unroll
  for (int dt = 0; dt < 4; ++dt) { oA[dt] = zero; oB[dt] = zero; }

  const int kcol0 = (quad ^ (l16 & 7)) * 8;   // swizzled frag column (shorts)
  const int ntiles = 64 - p;                  // key tiles 0..63-p

  stage_kv4(Kp, Vp, 0, k_lds[0], v_lds[0], tid, wave);

  for (int jt = 0; jt < ntiles; ++jt) {
    __syncthreads();   // stage(jt) visible; other buffer free for restage
    if (jt + 1 < ntiles)
      stage_kv4(Kp, Vp, (jt + 1) * 64, k_lds[(jt + 1) & 1], v_lds[(jt + 1) & 1], tid, wave);

    const unsigned short* kb = k_lds[jt & 1];
    const unsigned short* vb = v_lds[jt & 1];
    const int j0 = jt * 64;
    const bool actA = jt <= p;                 // wave-uniform

    bf16x8 kf[8];
#pragma unroll
    for (int i = 0; i < 4; ++i) {
      kf[2 * i]     = *(const bf16x8*)(kb + (16 * i + l16) * 64 + kcol0);
      kf[2 * i + 1] = *(const bf16x8*)(kb + (16 * i + l16) * 64 + (kcol0 ^ 32));
    }

    f32x4 sA[4], sB[4];
    if (actA) {
      qk_score(kf, qfA, sA);
      if (jt == p) exp_write<true>(sA, prowA, j0, qA0, l16, quad);
      else         exp_write<false>(sA, prowA, j0, qA0, l16, quad);
    }
    qk_score(kf, qfB, sB);
    if (jt == ntiles - 1) exp_write<true>(sB, prowB, j0, qB0, l16, quad);
    else                  exp_write<false>(sB, prowB, j0, qB0, l16, quad);

    LGKM_WAIT();             // wave-local: P writes committed (vmcnt untouched)

    // V-frags read ONCE, shared by both halves
    bf16x8 vf[8];
#pragma unroll
    for (int dt = 0; dt < 4; ++dt) {
      vf[2 * dt]     = *(const bf16x8*)(vb + (16 * dt + l16) * 64 + kcol0);
      vf[2 * dt + 1] = *(const bf16x8*)(vb + (16 * dt + l16) * 64 + (kcol0 ^ 32));
    }

    if (actA) {
      bf16x8 pf0 = *(const bf16x8*)(prowA + l16 * PSTR + quad * 8);
      bf16x8 pf1 = *(const bf16x8*)(prowA + l16 * PSTR + 32 + quad * 8);
      lA = mfma16(pf1, ones, mfma16(pf0, ones, lA));
#pragma unroll
      for (int dt = 0; dt < 4; ++dt)
        oA[dt] = mfma16(pf1, vf[2 * dt + 1], mfma16(pf0, vf[2 * dt], oA[dt]));
    }
    {
      bf16x8 pf0 = *(const bf16x8*)(prowB + l16 * PSTR + quad * 8);
      bf16x8 pf1 = *(const bf16x8*)(prowB + l16 * PSTR + 32 + quad * 8);
      lB = mfma16(pf1, ones, mfma16(pf0, ones, lB));
#pragma unroll
      for (int dt = 0; dt < 4; ++dt)
        oB[dt] = mfma16(pf1, vf[2 * dt + 1], mfma16(pf0, vf[2 * dt], oB[dt]));
    }
  }

  // l is in C-layout: row (quad*4+r) matches o rows; all 16 cols hold the same value.
  const int b = bh / NHEAD, h = bh - b * NHEAD;
#pragma unroll
  for (int r = 0; r < 4; ++r) {
    const int qrow = quad * 4 + r;
    float invA = 1.0f / lA[r], invB = 1.0f / lB[r];
    size_t rowA = (size_t)(b * TSEQ + qA0 + qrow) * CDIM + h * 64;
    size_t rowB = (size_t)(b * TSEQ + qB0 + qrow) * CDIM + h * 64;
#pragma unroll
    for (int dt = 0; dt < 4; ++dt) {
      y[rowA + dt * 16 + l16] = f2bf(oA[dt][r] * invA);
      y[rowB + dt * 16 + l16] = f2bf(oB[dt][r] * invB);
    }
  }
}

// ---------------- launch ----------------

extern "C" void kernel_launch(void* const* d_in, const int* in_sizes, int n_in,
                              void* d_out, int out_size, void* d_ws, size_t ws_size,
                              hipStream_t stream) {
  const float* x      = (const float*)d_in[0];
  const float* W_attn = (const float*)d_in[1];
  const float* b_attn = (const float*)d_in[2];
  const float* W_proj = (const float*)d_in[3];
  const float* b_proj = (const float*)d_in[4];
  float* out = (float*)d_out;

  unsigned short* xb    = (unsigned short*)d_ws;                  // [8192,768] bf16 (later reused as y)
  unsigned short* WaT   = xb + (size_t)BT_TOT * CDIM;             // [2304,768]
  unsigned short* WpT   = WaT + (size_t)C3 * CDIM;                // [768,768]
  unsigned short* qbuf  = WpT + (size_t)CDIM * CDIM;              // [24,4096,64]
  unsigned short* kbuf  = qbuf + (size_t)2 * NHEAD * TSEQ * 64;   // [24,4096,64]
  unsigned short* vtbuf = kbuf + (size_t)2 * NHEAD * TSEQ * 64;   // [24,64,4096]
  unsigned short* ybuf  = xb;  // x dead after GEMM1

  cast_f32_bf16<<<(BT_TOT * CDIM) / 1024, 256, 0, stream>>>(x, xb, BT_TOT * CDIM);
  transpose_cast<<<dim3(C3 / 32, CDIM / 32), dim3(32, 8), 0, stream>>>(W_attn, WaT, CDIM, C3);
  transpose_cast<<<dim3(CDIM / 32, CDIM / 32), dim3(32, 8), 0, stream>>>(W_proj, WpT, CDIM, CDIM);

  gemm_qkv_kernel<<<dim3(C3 / 128, BT_TOT / 128), 256, 0, stream>>>(xb, WaT, b_attn,
                                                                    qbuf, kbuf, vtbuf);
  attn_kernel<<<dim3(24 * 32), 256, 0, stream>>>(qbuf, kbuf, vtbuf, ybuf);
  gemm_out_kernel<<<dim3(CDIM / 128, BT_TOT / 128), 256, 0, stream>>>(ybuf, WpT, b_proj, out);
}